// Round 7
// baseline (51710.529 us; speedup 1.0000x reference)
//
#include <hip/hip_runtime.h>
#include <math.h>

// Problem dims (fixed by reference)
#define BB 32
#define SS 512
#define VV 30522
#define EE 768
#define HH 768
#define TT 9
#define G4 (4*HH)   // 3072
#define NBLK 96     // persistent LSTM grid: 96 blocks (PROVEN co-resident r1/r5)

// ---------------------------------------------------------------------------
// Embedding gather: x[row][:] = emb[ids[row]][:]
__global__ void embed_kernel(const int* __restrict__ ids,
                             const float* __restrict__ emb,
                             float* __restrict__ x) {
    const int row = blockIdx.x;
    const int e4  = threadIdx.x;           // 0..191
    const int id  = ids[row];
    *(float4*)&x[(size_t)row * EE + e4 * 4] =
        *(const float4*)&emb[(size_t)id * EE + e4 * 4];
}

// ---------------------------------------------------------------------------
// fp32 GEMM (pure fp32 accumulate, replicating an fp32 numpy reference):
// C[M,N] = A[M,K] @ W[N,K]^T + b1[N] + b2[N]
__global__ __launch_bounds__(256) void gemm_simple(
    const float* __restrict__ A, const float* __restrict__ W,
    const float* __restrict__ bias1, const float* __restrict__ bias2,
    float* __restrict__ C, int M, int N, int K) {
    __shared__ float As[16][65];
    __shared__ float Ws[16][65];
    const int tid = threadIdx.x;
    const int tx = tid & 15, ty = tid >> 4;
    const int m0 = blockIdx.y * 64, n0 = blockIdx.x * 64;
    float acc[4][4];
    #pragma unroll
    for (int i = 0; i < 4; ++i)
        #pragma unroll
        for (int j = 0; j < 4; ++j) acc[i][j] = 0.f;

    for (int k0 = 0; k0 < K; k0 += 16) {
        #pragma unroll
        for (int i = 0; i < 4; ++i) {
            int r = ty + i * 16;            // 0..63
            As[tx][r] = A[(size_t)(m0 + r) * K + k0 + tx];
            Ws[tx][r] = W[(size_t)(n0 + r) * K + k0 + tx];
        }
        __syncthreads();
        #pragma unroll
        for (int kk = 0; kk < 16; ++kk) {
            float ar[4], br[4];
            #pragma unroll
            for (int i = 0; i < 4; ++i) ar[i] = As[kk][ty * 4 + i];
            #pragma unroll
            for (int j = 0; j < 4; ++j) br[j] = Ws[kk][tx * 4 + j];
            #pragma unroll
            for (int i = 0; i < 4; ++i)
                #pragma unroll
                for (int j = 0; j < 4; ++j) acc[i][j] += ar[i] * br[j];
        }
        __syncthreads();
    }
    #pragma unroll
    for (int i = 0; i < 4; ++i) {
        int r = m0 + ty * 4 + i;
        #pragma unroll
        for (int j = 0; j < 4; ++j) {
            int c = n0 + tx * 4 + j;
            C[(size_t)r * N + c] = acc[i][j] + bias1[c] + bias2[c];
        }
    }
}

// ---------------------------------------------------------------------------
// Pack Whh [3072,768] into wpk[u][k][g]: wpk[(u*768+k)*4+g] = Whh[(g*768+u)*768+k]
// (VERBATIM r1 kernel -- proven.)
__global__ __launch_bounds__(256) void pack_whh(const float* __restrict__ Whh,
                                                float* __restrict__ wpk) {
    const int id = blockIdx.x * 256 + threadIdx.x;   // over 768*768
    const int u = id / 768;
    const int k = id - u * 768;
    float4 o;
    o.x = Whh[(size_t)(0 * 768 + u) * 768 + k];
    o.y = Whh[(size_t)(1 * 768 + u) * 768 + k];
    o.z = Whh[(size_t)(2 * 768 + u) * 768 + k];
    o.w = Whh[(size_t)(3 * 768 + u) * 768 + k];
    *(float4*)&wpk[(size_t)id * 4] = o;
}

// ---------------------------------------------------------------------------
// Zero the grid-barrier counters (must run each launch / graph replay).
__global__ void init_bars(unsigned* __restrict__ bar) {
    if (threadIdx.x < 2) bar[threadIdx.x] = 0u;
}

// ---------------------------------------------------------------------------
// Persistent full-layer LSTM, PURE fp32, one launch per layer.
// BIT-IDENTICAL math to r5 (passed, absmax 0.0): per (u,b,gate) ONE
// ascending-k fp32 FMA chain; gate expressions in r5's exact order.
//
// STRUCTURE (LDS-instruction-economy optimum; r6 post-mortem):
//   96 blocks x 256 threads.  Block owns 8 u's.  ONE compute wave (wave 0),
//   lane = (ul = tid>>3, bq = tid&7), tile = 1u x 4b x 4gates:
//   per k: 1 LDS b128 W (wpk[u][k][4g], addr k*8+ul -> 8 distinct float4 =
//   contiguous 128B, conflict-free) + 1 LDS b128 h (hs[kk*8+bq], same
//   pattern) -> 16 fmac.  LDS 18.4Kcy < VALU 24.6Kcy per step -> VALU-bound.
//   All 16 sums live in the owner's registers: NO cross-lane exchange.
//   h staged from global in 6 double-buffered 16KB chunks (128 k x 32 b):
//   waves 1-3 stage chunk c+1 while wave 0 computes chunk c (disjoint
//   buffers, one __syncthreads per chunk; r1's staging pattern).
//   Grid barrier: VERBATIM r1/r5 scheme.
__global__ __launch_bounds__(256) void lstm_layer_persist(
    const float* __restrict__ xW,    // [B*S*3072] input proj + biases
    const float* __restrict__ wpk,   // [768*768*4] packed Whh
    float* __restrict__ h_out,       // [B*S*768]
    float* __restrict__ hTa,         // ping [768*32], [u*32+b]
    float* __restrict__ hTb,         // pong
    unsigned* __restrict__ bar) {    // one zeroed counter
    extern __shared__ float smem[];
    float4* wlds4 = (float4*)smem;           // 6144 float4 = 96 KB, idx k*8+ul
    float*  hs    = smem + 24576;            // 2 x 4096 floats = 32 KB
    const int tid = threadIdx.x;
    const int ul  = tid >> 3;            // 0..7 (only meaningful for wave 0)
    const int bq  = tid & 7;             // 0..7
    const int u   = blockIdx.x * 8 + ul;
    const bool owner = (tid < 64);       // wave 0: computes + gates + stores

    // one-time W stage (VERBATIM r1): wlds4[k*8+uu] = wpk4[(blk*8+uu)*768+k]
    const float4* wp4 = (const float4*)wpk;
    for (int idx = tid; idx < 6144; idx += 256) {
        const int k  = idx >> 3;
        const int uu = idx & 7;
        wlds4[idx] = wp4[(size_t)(blockIdx.x * 8 + uu) * 768 + k];
    }
    __syncthreads();

    float cc[4] = {0.f, 0.f, 0.f, 0.f};

    for (int t = 0; t < SS; ++t) {
        // owner issues xW loads early; latency hides under the matvec
        float xg[4][4];
        if (owner) {
            #pragma unroll
            for (int j = 0; j < 4; ++j) {
                const size_t row = (size_t)(bq * 4 + j) * SS + t;
                #pragma unroll
                for (int gg = 0; gg < 4; ++gg)
                    xg[j][gg] = xW[row * G4 + gg * HH + u];
            }
        }

        float4 aI = {0,0,0,0}, aF = {0,0,0,0}, aG = {0,0,0,0}, aO = {0,0,0,0};
        if (t > 0) {
            const float4* hp = (const float4*)((t & 1) ? hTb : hTa);

            // prologue: ALL threads stage chunk 0 (1024 float4, 4 each)
            {
                float4* dst = (float4*)hs;
                #pragma unroll
                for (int r = 0; r < 4; ++r) dst[r * 256 + tid] = hp[r * 256 + tid];
            }
            __syncthreads();

            // 6 chunks of 128 k, double-buffered
            for (int c = 0; c < 6; ++c) {
                if (tid >= 64 && c + 1 < 6) {
                    // waves 1-3 stage chunk c+1 into the other buffer
                    const float4* src = hp + (size_t)(c + 1) * 1024;
                    float4* dst = (float4*)(hs + ((c + 1) & 1) * 4096);
                    for (int i = tid - 64; i < 1024; i += 192) dst[i] = src[i];
                }
                if (owner) {
                    const float4* hb = (const float4*)(hs + (c & 1) * 4096);
                    const float4* wb = wlds4 + c * 128 * 8;
                    #pragma unroll 8
                    for (int kk = 0; kk < 128; ++kk) {
                        const float4 w4 = wb[kk * 8 + ul];  // 4 gates of u at k
                        const float4 hv = hb[kk * 8 + bq];  // 4 batches at k
                        // ascending-k chains per (gate,batch) -- r5's order
                        aI.x += w4.x*hv.x; aI.y += w4.x*hv.y; aI.z += w4.x*hv.z; aI.w += w4.x*hv.w;
                        aF.x += w4.y*hv.x; aF.y += w4.y*hv.y; aF.z += w4.y*hv.z; aF.w += w4.y*hv.w;
                        aG.x += w4.z*hv.x; aG.y += w4.z*hv.y; aG.z += w4.z*hv.z; aG.w += w4.z*hv.w;
                        aO.x += w4.w*hv.x; aO.y += w4.w*hv.y; aO.z += w4.w*hv.z; aO.w += w4.w*hv.w;
                    }
                }
                __syncthreads();
            }
        }

        if (owner) {
            const float si_[4] = {aI.x, aI.y, aI.z, aI.w};
            const float sf_[4] = {aF.x, aF.y, aF.z, aF.w};
            const float sk_[4] = {aG.x, aG.y, aG.z, aG.w};
            const float so_[4] = {aO.x, aO.y, aO.z, aO.w};
            float* hTo = (t & 1) ? hTa : hTb;   // step t writes hbuf[(t+1)&1]
            float hvv[4];
            #pragma unroll
            for (int j = 0; j < 4; ++j) {
                const float gi = si_[j] + xg[j][0];   // r5's exact order
                const float gf = sf_[j] + xg[j][1];
                const float gg = sk_[j] + xg[j][2];
                const float go = so_[j] + xg[j][3];
                const float sI = 1.f / (1.f + expf(-gi));
                const float sF = 1.f / (1.f + expf(-gf));
                const float sO = 1.f / (1.f + expf(-go));
                const float tG = tanhf(gg);
                cc[j] = sF * cc[j] + sI * tG;
                const float h = sO * tanhf(cc[j]);
                hvv[j] = h;
                h_out[((size_t)(bq * 4 + j) * SS + t) * HH + u] = h;
            }
            *(float4*)&hTo[u * 32 + bq * 4] =
                make_float4(hvv[0], hvv[1], hvv[2], hvv[3]);
        }

        if (t < SS - 1) {
            // grid barrier: all blocks must finish step t before t+1
            __syncthreads();                 // drains this block's stores
            if (tid == 0) {
                __builtin_amdgcn_fence(__ATOMIC_RELEASE, "agent");
                atomicAdd(bar, 1u);          // device scope by default
                const unsigned target = (unsigned)(t + 1) * NBLK;
                while (__hip_atomic_load(bar, __ATOMIC_RELAXED,
                                         __HIP_MEMORY_SCOPE_AGENT) < target)
                    __builtin_amdgcn_s_sleep(1);
                __builtin_amdgcn_fence(__ATOMIC_ACQUIRE, "agent");
            }
            __syncthreads();
        }
    }
}

// ---------------------------------------------------------------------------
// Scalar logits + log_softmax, pure fp32, one thread per row.
__global__ __launch_bounds__(256) void logits_kernel(
    const float* __restrict__ h, const float* __restrict__ Wout,
    const float* __restrict__ bout, float* __restrict__ logp) {
    const int row = blockIdx.x * 256 + threadIdx.x;   // 0..16383
    const float* hr = &h[(size_t)row * HH];
    float lg[TT];
    for (int tt = 0; tt < TT; ++tt) {
        const float* wr = &Wout[tt * HH];
        float ps = 0.f;
        for (int k = 0; k < HH; ++k) ps += hr[k] * wr[k];
        lg[tt] = ps + bout[tt];
    }
    float mx = lg[0];
    for (int tt = 1; tt < TT; ++tt) mx = fmaxf(mx, lg[tt]);
    float sm = 0.f;
    for (int tt = 0; tt < TT; ++tt) sm += expf(lg[tt] - mx);
    float lse = mx + logf(sm);
    for (int tt = 0; tt < TT; ++tt) logp[(size_t)row * TT + tt] = lg[tt] - lse;
}

// ---------------------------------------------------------------------------
// CRF forward (loss), pure fp32: wave per batch, lanes = next-tag. 32 blocks.
#define NEG_INF_F -3.0e38f
__global__ __launch_bounds__(64) void crf_forward(
    const float* __restrict__ logp, const int* __restrict__ labels,
    const int* __restrict__ mask, const float* __restrict__ start_t,
    const float* __restrict__ end_t, const float* __restrict__ trans,
    float* __restrict__ bstats) {
    const int b = blockIdx.x;
    const int lane = threadIdx.x;
    const int j = lane < TT ? lane : TT - 1;
    const float* em = logp + (size_t)b * SS * TT;
    const int* mk = mask + b * SS;
    const int* lb = labels + b * SS;
    float tr[TT];
    #pragma unroll
    for (int i = 0; i < TT; ++i) tr[i] = trans[i * TT + j];
    float sc = start_t[j] + em[j];

    for (int t = 1; t < SS; ++t) {
        const int m = mk[t];
        const float e = em[t * TT + j];
        float v[TT];
        #pragma unroll
        for (int i = 0; i < TT; ++i) v[i] = __shfl(sc, i) + tr[i];
        float mx = v[0];
        #pragma unroll
        for (int i = 1; i < TT; ++i) mx = fmaxf(mx, v[i]);
        float smv = 0.f;
        #pragma unroll
        for (int i = 0; i < TT; ++i) smv += expf(v[i] - mx);
        float nxt = mx + logf(smv) + e;
        sc = m ? nxt : sc;
    }
    float fin = sc + end_t[j];
    float fv[TT];
    #pragma unroll
    for (int i = 0; i < TT; ++i) fv[i] = __shfl(fin, i);
    float mx = fv[0];
    #pragma unroll
    for (int i = 1; i < TT; ++i) mx = fmaxf(mx, fv[i]);
    float smv = 0.f;
    #pragma unroll
    for (int i = 0; i < TT; ++i) smv += expf(fv[i] - mx);
    float denom = mx + logf(smv);
    // numerator + token count
    float np = 0.f; int ic = 0;
    for (int t = lane; t < SS; t += 64) {
        int m = mk[t];
        ic += m;
        if (t > 0 && m) {
            int tg = lb[t], tp = lb[t - 1];
            np += trans[tp * TT + tg] + em[t * TT + tg];
        }
    }
    for (int off = 32; off; off >>= 1) {
        np += __shfl_down(np, off);
        ic += __shfl_down(ic, off);
    }
    if (lane == 0) {
        int tg0 = lb[0];
        np += start_t[tg0] + em[tg0];
        int tgl = lb[ic - 1];              // mask is a contiguous prefix
        np += end_t[tgl];
        bstats[b * 3 + 0] = np;
        bstats[b * 3 + 1] = denom;
        bstats[b * 3 + 2] = (float)ic;
    }
}

// ---------------------------------------------------------------------------
// Fully scalar Viterbi decode, pure fp32: one thread per batch.
__global__ __launch_bounds__(64) void crf_decode(
    const float* __restrict__ logp, const int* __restrict__ mask,
    const float* __restrict__ start_t, const float* __restrict__ end_t,
    const float* __restrict__ trans, float* __restrict__ preds) {
    __shared__ unsigned char bp[SS][TT];
    if (threadIdx.x != 0) return;
    const int b = blockIdx.x;
    const float* em = logp + (size_t)b * SS * TT;
    const int* mk = mask + b * SS;
    float sc[TT], nx[TT];
    for (int jj = 0; jj < TT; ++jj) sc[jj] = start_t[jj] + em[jj];

    for (int t = 1; t < SS; ++t) {
        const int m = mk[t];
        for (int jj = 0; jj < TT; ++jj) {
            float bmv = NEG_INF_F; int bi = 0;
            for (int i = 0; i < TT; ++i) {
                float v = sc[i] + trans[i * TT + jj];
                if (v > bmv) { bmv = v; bi = i; }     // first max wins
            }
            nx[jj] = bmv + em[t * TT + jj];
            bp[t][jj] = (unsigned char)(m ? bi : jj); // identity when masked
        }
        if (m) for (int jj = 0; jj < TT; ++jj) sc[jj] = nx[jj];
    }
    float bm = NEG_INF_F; int best = 0;
    for (int jj = 0; jj < TT; ++jj) {
        float v = sc[jj] + end_t[jj];
        if (v > bm) { bm = v; best = jj; }
    }
    int tag = best;
    preds[b * SS + (SS - 1)] = (float)(mk[SS - 1] ? tag : 0);
    for (int t = SS - 1; t >= 1; --t) {
        tag = bp[t][tag];
        preds[b * SS + t - 1] = (float)(mk[t - 1] ? tag : 0);
    }
}

__global__ void loss_kernel(const float* __restrict__ bstats,
                            float* __restrict__ out) {
    const int lane = threadIdx.x;
    float nd = 0.f, c = 0.f;
    if (lane < 32) {
        nd = bstats[lane * 3] - bstats[lane * 3 + 1];
        c  = bstats[lane * 3 + 2];
    }
    for (int off = 32; off; off >>= 1) {
        nd += __shfl_down(nd, off);
        c  += __shfl_down(c, off);
    }
    if (lane == 0) out[0] = -nd / c;
}

// ---------------------------------------------------------------------------
extern "C" void kernel_launch(void* const* d_in, const int* in_sizes, int n_in,
                              void* d_out, int out_size, void* d_ws, size_t ws_size,
                              hipStream_t stream) {
    const int*   ids   = (const int*)d_in[0];
    const int*   amask = (const int*)d_in[1];
    const int*   labels= (const int*)d_in[2];
    const float* emb   = (const float*)d_in[3];
    const float* Wih0  = (const float*)d_in[4];
    const float* Whh0  = (const float*)d_in[5];
    const float* bih0  = (const float*)d_in[6];
    const float* bhh0  = (const float*)d_in[7];
    const float* Wih1  = (const float*)d_in[8];
    const float* Whh1  = (const float*)d_in[9];
    const float* bih1  = (const float*)d_in[10];
    const float* bhh1  = (const float*)d_in[11];
    const float* Wout  = (const float*)d_in[12];
    const float* boutp = (const float*)d_in[13];
    const float* st    = (const float*)d_in[14];
    const float* et    = (const float*)d_in[15];
    const float* trp   = (const float*)d_in[16];

    // workspace layout (floats). Same known-good footprint as r1/r5.
    float* ws     = (float*)d_ws;
    float* slab   = ws;                       // 12,582,912 (x / h0 / h1)
    float* xW     = slab + 12582912;          // 50,331,648 (gate pre-acts)
    float* hTa    = xW + 50331648;            // 24,576 (ping)
    float* hTb    = hTa + 24576;              // 24,576 (pong)
    float* wpk    = hTb + 24576;              // 2,359,296 (packed Whh)
    float* cb     = wpk + 2359296;            // 24,576 (barrier counters)
    float* logp   = cb + 24576;               // 147,456
    float* bstats = logp + 147456;            // 96
    unsigned* bar = (unsigned*)cb;
    float* out    = (float*)d_out;

    // allow 128 KB dynamic LDS for the persistent kernel (1 block/CU;
    // this exact attr value was proven in round 1)
    static bool attr_done = false;
    if (!attr_done) {
        hipFuncSetAttribute((const void*)lstm_layer_persist,
                            hipFuncAttributeMaxDynamicSharedMemorySize,
                            131072);
        attr_done = true;
    }

    dim3 ggrid(G4 / 64, (BB * SS) / 64);      // (48, 256)

    init_bars<<<1, 64, 0, stream>>>(bar);

    // layer 0
    embed_kernel<<<BB * SS, EE / 4, 0, stream>>>(ids, emb, slab);
    gemm_simple<<<ggrid, 256, 0, stream>>>(slab, Wih0, bih0, bhh0, xW,
                                           BB * SS, G4, EE);
    pack_whh<<<(HH * HH) / 256, 256, 0, stream>>>(Whh0, wpk);
    lstm_layer_persist<<<NBLK, 256, 131072, stream>>>(xW, wpk, slab,
                                                      hTa, hTb, bar + 0);

    // layer 1
    gemm_simple<<<ggrid, 256, 0, stream>>>(slab, Wih1, bih1, bhh1, xW,
                                           BB * SS, G4, HH);
    pack_whh<<<(HH * HH) / 256, 256, 0, stream>>>(Whh1, wpk);
    lstm_layer_persist<<<NBLK, 256, 131072, stream>>>(xW, wpk, slab,
                                                      hTa, hTb, bar + 1);

    // projection + log_softmax (scalar fp32)
    logits_kernel<<<(BB * SS) / 256, 256, 0, stream>>>(slab, Wout, boutp, logp);

    // CRF loss + scalar decode (fp32)
    crf_forward<<<32, 64, 0, stream>>>(logp, labels, amask, st, et, trp, bstats);
    crf_decode<<<32, 64, 0, stream>>>(logp, amask, st, et, trp, out + 1);
    loss_kernel<<<1, 64, 0, stream>>>(bstats, out);
}

// Round 8
// 29838.986 us; speedup vs baseline: 1.7330x; 1.7330x over previous
//
#include <hip/hip_runtime.h>
#include <math.h>

// Problem dims (fixed by reference)
#define BB 32
#define SS 512
#define VV 30522
#define EE 768
#define HH 768
#define TT 9
#define G4 (4*HH)   // 3072
#define NBLK 96     // persistent LSTM grid: 96 blocks (PROVEN co-resident)

// ---------------------------------------------------------------------------
// Embedding gather: x[row][:] = emb[ids[row]][:]
__global__ void embed_kernel(const int* __restrict__ ids,
                             const float* __restrict__ emb,
                             float* __restrict__ x) {
    const int row = blockIdx.x;
    const int e4  = threadIdx.x;           // 0..191
    const int id  = ids[row];
    *(float4*)&x[(size_t)row * EE + e4 * 4] =
        *(const float4*)&emb[(size_t)id * EE + e4 * 4];
}

// ---------------------------------------------------------------------------
// fp32 GEMM (pure fp32 accumulate, replicating an fp32 numpy reference):
// C[M,N] = A[M,K] @ W[N,K]^T + b1[N] + b2[N]
__global__ __launch_bounds__(256) void gemm_simple(
    const float* __restrict__ A, const float* __restrict__ W,
    const float* __restrict__ bias1, const float* __restrict__ bias2,
    float* __restrict__ C, int M, int N, int K) {
    __shared__ float As[16][65];
    __shared__ float Ws[16][65];
    const int tid = threadIdx.x;
    const int tx = tid & 15, ty = tid >> 4;
    const int m0 = blockIdx.y * 64, n0 = blockIdx.x * 64;
    float acc[4][4];
    #pragma unroll
    for (int i = 0; i < 4; ++i)
        #pragma unroll
        for (int j = 0; j < 4; ++j) acc[i][j] = 0.f;

    for (int k0 = 0; k0 < K; k0 += 16) {
        #pragma unroll
        for (int i = 0; i < 4; ++i) {
            int r = ty + i * 16;            // 0..63
            As[tx][r] = A[(size_t)(m0 + r) * K + k0 + tx];
            Ws[tx][r] = W[(size_t)(n0 + r) * K + k0 + tx];
        }
        __syncthreads();
        #pragma unroll
        for (int kk = 0; kk < 16; ++kk) {
            float ar[4], br[4];
            #pragma unroll
            for (int i = 0; i < 4; ++i) ar[i] = As[kk][ty * 4 + i];
            #pragma unroll
            for (int j = 0; j < 4; ++j) br[j] = Ws[kk][tx * 4 + j];
            #pragma unroll
            for (int i = 0; i < 4; ++i)
                #pragma unroll
                for (int j = 0; j < 4; ++j) acc[i][j] += ar[i] * br[j];
        }
        __syncthreads();
    }
    #pragma unroll
    for (int i = 0; i < 4; ++i) {
        int r = m0 + ty * 4 + i;
        #pragma unroll
        for (int j = 0; j < 4; ++j) {
            int c = n0 + tx * 4 + j;
            C[(size_t)r * N + c] = acc[i][j] + bias1[c] + bias2[c];
        }
    }
}

// ---------------------------------------------------------------------------
// Pack Whh [3072,768] into wpk[u][k][g]: wpk[(u*768+k)*4+g] = Whh[(g*768+u)*768+k]
// (VERBATIM r1 kernel -- proven.)
__global__ __launch_bounds__(256) void pack_whh(const float* __restrict__ Whh,
                                                float* __restrict__ wpk) {
    const int id = blockIdx.x * 256 + threadIdx.x;   // over 768*768
    const int u = id / 768;
    const int k = id - u * 768;
    float4 o;
    o.x = Whh[(size_t)(0 * 768 + u) * 768 + k];
    o.y = Whh[(size_t)(1 * 768 + u) * 768 + k];
    o.z = Whh[(size_t)(2 * 768 + u) * 768 + k];
    o.w = Whh[(size_t)(3 * 768 + u) * 768 + k];
    *(float4*)&wpk[(size_t)id * 4] = o;
}

// ---------------------------------------------------------------------------
// Zero the grid-barrier counters (must run each launch / graph replay).
__global__ void init_bars(unsigned* __restrict__ bar) {
    if (threadIdx.x < 2) bar[threadIdx.x] = 0u;
}

// ---------------------------------------------------------------------------
// Persistent full-layer LSTM, PURE fp32, one launch per layer.
// BIT-IDENTICAL math to r1/r5 (both passed, absmax 0.0): per (u,b,gate) ONE
// ascending-k fp32 FMA chain (a0 += w.x*h; a1 += w.y*h; ...), gate
// expressions in the same order (a + xW).
//
// STRUCTURE (r7 post-mortem: r1 sits exactly at the LDS-instruction
// throughput wall, 4 waves x 768 x (b128+b32) = 54.7Kcy):
//   96 blocks x 512 threads (8 waves).  WAVE = ONE u (u = blk*8 + waveid):
//   the W address depends only on (u,k) -> WAVE-UNIFORM (readfirstlane) ->
//   compiler emits scalar s_load from wpk[u][k][4g] (contiguous 64B/4k) on
//   the SMEM pipe -- W leaves the LDS pipe entirely.
//   Lane = batch (b = lane&31; upper 32 lanes harmlessly duplicate, keeping
//   the hot loop divergence-free so scalarization is legal).
//   h_{t-1} stored [b][u] in global, staged ONCE per step into transposed
//   LDS hs[b][772-pad]: each lane reads its own contiguous float4 = 4 k per
//   ds_read_b128 (192 per wave per step), 32 rows at stride 772 (772%32=4)
//   -> banks covered at the data minimum.
//   8 waves = 2/SIMD: LDS/SMEM latency covered by TLP (r7 failure mode).
//   Grid barrier: VERBATIM r1 scheme (single monotonic device-scope
//   counter, target (t+1)*NBLK, s_sleep spin, agent release/acquire).
__global__ __launch_bounds__(512) void lstm_layer_persist(
    const float* __restrict__ xW,    // [B*S*3072] input proj + biases
    const float* __restrict__ wpk,   // [768*768*4] packed Whh
    float* __restrict__ h_out,       // [B*S*768]
    float* __restrict__ hTa,         // ping [32*768], layout [b][u]
    float* __restrict__ hTb,         // pong
    unsigned* __restrict__ bar) {    // one zeroed counter
    extern __shared__ float smem[];  // hs: 32 rows x 772 floats = 98816 B
    const int tid = threadIdx.x;
    const int w   = __builtin_amdgcn_readfirstlane(tid >> 6);  // wave 0..7
    const int b   = tid & 31;            // batch (pairs of lanes duplicate)
    const int u   = blockIdx.x * 8 + w;
    const bool owner = (tid & 63) < 32;  // lower half-wave owns (u,b)

    const float4* wp4 = (const float4*)wpk + (size_t)u * 768;  // uniform base
    float cc = 0.f;                       // cell state for (u,b)

    for (int t = 0; t < SS; ++t) {
        // owners issue xW loads early; latency hides under the matvec
        float xg0, xg1, xg2, xg3;
        if (owner) {
            const size_t row = (size_t)b * SS + t;
            xg0 = xW[row * G4 + 0 * HH + u];
            xg1 = xW[row * G4 + 1 * HH + u];
            xg2 = xW[row * G4 + 2 * HH + u];
            xg3 = xW[row * G4 + 3 * HH + u];
        }

        float a0 = 0.f, a1 = 0.f, a2 = 0.f, a3 = 0.f;
        if (t > 0) {
            const float* hT_in = (t & 1) ? hTb : hTa;
            // stage full h (24576 floats) into transposed padded LDS
            {
                const float4* src = (const float4*)hT_in;
                for (int i = tid; i < 6144; i += 512) {
                    const int bb = i / 192;          // 0..31
                    const int u4 = i - bb * 192;     // 0..191
                    *(float4*)&smem[bb * 772 + u4 * 4] = src[bb * 192 + u4];
                }
            }
            __syncthreads();

            const float4* hrow = (const float4*)(smem + b * 772);
            #pragma unroll 4
            for (int k4 = 0; k4 < 192; ++k4) {
                const float4 h4 = hrow[k4];          // 4 k's of h (LDS b128)
                const float4 w0 = wp4[k4 * 4 + 0];   // uniform -> s_load
                const float4 w1 = wp4[k4 * 4 + 1];
                const float4 w2 = wp4[k4 * 4 + 2];
                const float4 w3 = wp4[k4 * 4 + 3];
                // ascending-k chains, r1's exact per-k order
                a0 += w0.x * h4.x; a1 += w0.y * h4.x; a2 += w0.z * h4.x; a3 += w0.w * h4.x;
                a0 += w1.x * h4.y; a1 += w1.y * h4.y; a2 += w1.z * h4.y; a3 += w1.w * h4.y;
                a0 += w2.x * h4.z; a1 += w2.y * h4.z; a2 += w2.z * h4.z; a3 += w2.w * h4.z;
                a0 += w3.x * h4.w; a1 += w3.y * h4.w; a2 += w3.z * h4.w; a3 += w3.w * h4.w;
            }
        }

        if (owner) {
            const float gi = a0 + xg0;        // r1's exact order: a + xW
            const float gf = a1 + xg1;
            const float gg = a2 + xg2;
            const float go = a3 + xg3;
            const float sI = 1.f / (1.f + expf(-gi));
            const float sF = 1.f / (1.f + expf(-gf));
            const float sO = 1.f / (1.f + expf(-go));
            const float tG = tanhf(gg);
            cc = sF * cc + sI * tG;
            const float h = sO * tanhf(cc);
            h_out[((size_t)b * SS + t) * HH + u] = h;
            float* hTo = (t & 1) ? hTa : hTb;   // step t writes hbuf[(t+1)&1]
            hTo[b * 768 + u] = h;               // [b][u] layout
        }

        if (t < SS - 1) {
            // grid barrier: all blocks must finish step t before t+1
            __syncthreads();                 // drains this block's stores
            if (tid == 0) {
                __builtin_amdgcn_fence(__ATOMIC_RELEASE, "agent");
                atomicAdd(bar, 1u);          // device scope by default
                const unsigned target = (unsigned)(t + 1) * NBLK;
                while (__hip_atomic_load(bar, __ATOMIC_RELAXED,
                                         __HIP_MEMORY_SCOPE_AGENT) < target)
                    __builtin_amdgcn_s_sleep(1);
                __builtin_amdgcn_fence(__ATOMIC_ACQUIRE, "agent");
            }
            __syncthreads();
        }
    }
}

// ---------------------------------------------------------------------------
// Scalar logits + log_softmax, pure fp32, one thread per row.
__global__ __launch_bounds__(256) void logits_kernel(
    const float* __restrict__ h, const float* __restrict__ Wout,
    const float* __restrict__ bout, float* __restrict__ logp) {
    const int row = blockIdx.x * 256 + threadIdx.x;   // 0..16383
    const float* hr = &h[(size_t)row * HH];
    float lg[TT];
    for (int tt = 0; tt < TT; ++tt) {
        const float* wr = &Wout[tt * HH];
        float ps = 0.f;
        for (int k = 0; k < HH; ++k) ps += hr[k] * wr[k];
        lg[tt] = ps + bout[tt];
    }
    float mx = lg[0];
    for (int tt = 1; tt < TT; ++tt) mx = fmaxf(mx, lg[tt]);
    float sm = 0.f;
    for (int tt = 0; tt < TT; ++tt) sm += expf(lg[tt] - mx);
    float lse = mx + logf(sm);
    for (int tt = 0; tt < TT; ++tt) logp[(size_t)row * TT + tt] = lg[tt] - lse;
}

// ---------------------------------------------------------------------------
// CRF forward (loss), pure fp32: wave per batch, lanes = next-tag. 32 blocks.
#define NEG_INF_F -3.0e38f
__global__ __launch_bounds__(64) void crf_forward(
    const float* __restrict__ logp, const int* __restrict__ labels,
    const int* __restrict__ mask, const float* __restrict__ start_t,
    const float* __restrict__ end_t, const float* __restrict__ trans,
    float* __restrict__ bstats) {
    const int b = blockIdx.x;
    const int lane = threadIdx.x;
    const int j = lane < TT ? lane : TT - 1;
    const float* em = logp + (size_t)b * SS * TT;
    const int* mk = mask + b * SS;
    const int* lb = labels + b * SS;
    float tr[TT];
    #pragma unroll
    for (int i = 0; i < TT; ++i) tr[i] = trans[i * TT + j];
    float sc = start_t[j] + em[j];

    for (int t = 1; t < SS; ++t) {
        const int m = mk[t];
        const float e = em[t * TT + j];
        float v[TT];
        #pragma unroll
        for (int i = 0; i < TT; ++i) v[i] = __shfl(sc, i) + tr[i];
        float mx = v[0];
        #pragma unroll
        for (int i = 1; i < TT; ++i) mx = fmaxf(mx, v[i]);
        float smv = 0.f;
        #pragma unroll
        for (int i = 0; i < TT; ++i) smv += expf(v[i] - mx);
        float nxt = mx + logf(smv) + e;
        sc = m ? nxt : sc;
    }
    float fin = sc + end_t[j];
    float fv[TT];
    #pragma unroll
    for (int i = 0; i < TT; ++i) fv[i] = __shfl(fin, i);
    float mx = fv[0];
    #pragma unroll
    for (int i = 1; i < TT; ++i) mx = fmaxf(mx, fv[i]);
    float smv = 0.f;
    #pragma unroll
    for (int i = 0; i < TT; ++i) smv += expf(fv[i] - mx);
    float denom = mx + logf(smv);
    // numerator + token count
    float np = 0.f; int ic = 0;
    for (int t = lane; t < SS; t += 64) {
        int m = mk[t];
        ic += m;
        if (t > 0 && m) {
            int tg = lb[t], tp = lb[t - 1];
            np += trans[tp * TT + tg] + em[t * TT + tg];
        }
    }
    for (int off = 32; off; off >>= 1) {
        np += __shfl_down(np, off);
        ic += __shfl_down(ic, off);
    }
    if (lane == 0) {
        int tg0 = lb[0];
        np += start_t[tg0] + em[tg0];
        int tgl = lb[ic - 1];              // mask is a contiguous prefix
        np += end_t[tgl];
        bstats[b * 3 + 0] = np;
        bstats[b * 3 + 1] = denom;
        bstats[b * 3 + 2] = (float)ic;
    }
}

// ---------------------------------------------------------------------------
// Fully scalar Viterbi decode, pure fp32: one thread per batch.
__global__ __launch_bounds__(64) void crf_decode(
    const float* __restrict__ logp, const int* __restrict__ mask,
    const float* __restrict__ start_t, const float* __restrict__ end_t,
    const float* __restrict__ trans, float* __restrict__ preds) {
    __shared__ unsigned char bp[SS][TT];
    if (threadIdx.x != 0) return;
    const int b = blockIdx.x;
    const float* em = logp + (size_t)b * SS * TT;
    const int* mk = mask + b * SS;
    float sc[TT], nx[TT];
    for (int jj = 0; jj < TT; ++jj) sc[jj] = start_t[jj] + em[jj];

    for (int t = 1; t < SS; ++t) {
        const int m = mk[t];
        for (int jj = 0; jj < TT; ++jj) {
            float bmv = NEG_INF_F; int bi = 0;
            for (int i = 0; i < TT; ++i) {
                float v = sc[i] + trans[i * TT + jj];
                if (v > bmv) { bmv = v; bi = i; }     // first max wins
            }
            nx[jj] = bmv + em[t * TT + jj];
            bp[t][jj] = (unsigned char)(m ? bi : jj); // identity when masked
        }
        if (m) for (int jj = 0; jj < TT; ++jj) sc[jj] = nx[jj];
    }
    float bm = NEG_INF_F; int best = 0;
    for (int jj = 0; jj < TT; ++jj) {
        float v = sc[jj] + end_t[jj];
        if (v > bm) { bm = v; best = jj; }
    }
    int tag = best;
    preds[b * SS + (SS - 1)] = (float)(mk[SS - 1] ? tag : 0);
    for (int t = SS - 1; t >= 1; --t) {
        tag = bp[t][tag];
        preds[b * SS + t - 1] = (float)(mk[t - 1] ? tag : 0);
    }
}

__global__ void loss_kernel(const float* __restrict__ bstats,
                            float* __restrict__ out) {
    const int lane = threadIdx.x;
    float nd = 0.f, c = 0.f;
    if (lane < 32) {
        nd = bstats[lane * 3] - bstats[lane * 3 + 1];
        c  = bstats[lane * 3 + 2];
    }
    for (int off = 32; off; off >>= 1) {
        nd += __shfl_down(nd, off);
        c  += __shfl_down(c, off);
    }
    if (lane == 0) out[0] = -nd / c;
}

// ---------------------------------------------------------------------------
extern "C" void kernel_launch(void* const* d_in, const int* in_sizes, int n_in,
                              void* d_out, int out_size, void* d_ws, size_t ws_size,
                              hipStream_t stream) {
    const int*   ids   = (const int*)d_in[0];
    const int*   amask = (const int*)d_in[1];
    const int*   labels= (const int*)d_in[2];
    const float* emb   = (const float*)d_in[3];
    const float* Wih0  = (const float*)d_in[4];
    const float* Whh0  = (const float*)d_in[5];
    const float* bih0  = (const float*)d_in[6];
    const float* bhh0  = (const float*)d_in[7];
    const float* Wih1  = (const float*)d_in[8];
    const float* Whh1  = (const float*)d_in[9];
    const float* bih1  = (const float*)d_in[10];
    const float* bhh1  = (const float*)d_in[11];
    const float* Wout  = (const float*)d_in[12];
    const float* boutp = (const float*)d_in[13];
    const float* st    = (const float*)d_in[14];
    const float* et    = (const float*)d_in[15];
    const float* trp   = (const float*)d_in[16];

    // workspace layout (floats). Same known-good footprint as r1/r5.
    float* ws     = (float*)d_ws;
    float* slab   = ws;                       // 12,582,912 (x / h0 / h1)
    float* xW     = slab + 12582912;          // 50,331,648 (gate pre-acts)
    float* hTa    = xW + 50331648;            // 24,576 (ping, [b][u])
    float* hTb    = hTa + 24576;              // 24,576 (pong)
    float* wpk    = hTb + 24576;              // 2,359,296 (packed Whh)
    float* cb     = wpk + 2359296;            // 24,576 (barrier counters)
    float* logp   = cb + 24576;               // 147,456
    float* bstats = logp + 147456;            // 96
    unsigned* bar = (unsigned*)cb;
    float* out    = (float*)d_out;

    // allow ~97 KB dynamic LDS for the persistent kernel (1 block/CU)
    static bool attr_done = false;
    if (!attr_done) {
        hipFuncSetAttribute((const void*)lstm_layer_persist,
                            hipFuncAttributeMaxDynamicSharedMemorySize,
                            131072);
        attr_done = true;
    }

    dim3 ggrid(G4 / 64, (BB * SS) / 64);      // (48, 256)

    init_bars<<<1, 64, 0, stream>>>(bar);

    // layer 0
    embed_kernel<<<BB * SS, EE / 4, 0, stream>>>(ids, emb, slab);
    gemm_simple<<<ggrid, 256, 0, stream>>>(slab, Wih0, bih0, bhh0, xW,
                                           BB * SS, G4, EE);
    pack_whh<<<(HH * HH) / 256, 256, 0, stream>>>(Whh0, wpk);
    lstm_layer_persist<<<NBLK, 512, 98816, stream>>>(xW, wpk, slab,
                                                     hTa, hTb, bar + 0);

    // layer 1
    gemm_simple<<<ggrid, 256, 0, stream>>>(slab, Wih1, bih1, bhh1, xW,
                                           BB * SS, G4, HH);
    pack_whh<<<(HH * HH) / 256, 256, 0, stream>>>(Whh1, wpk);
    lstm_layer_persist<<<NBLK, 512, 98816, stream>>>(xW, wpk, slab,
                                                     hTa, hTb, bar + 1);

    // projection + log_softmax (scalar fp32)
    logits_kernel<<<(BB * SS) / 256, 256, 0, stream>>>(slab, Wout, boutp, logp);

    // CRF loss + scalar decode (fp32)
    crf_forward<<<32, 64, 0, stream>>>(logp, labels, amask, st, et, trp, bstats);
    crf_decode<<<32, 64, 0, stream>>>(logp, amask, st, et, trp, out + 1);
    loss_kernel<<<1, 64, 0, stream>>>(bstats, out);
}